// Round 1
// 494.296 us; speedup vs baseline: 1.0333x; 1.0333x over previous
//
#include <hip/hip_runtime.h>

// CorrelationLayer1D via bf16 MFMA band-matmul, v2 (latency-oriented rework).
// out[b,d,h,w] = sum_c x1[b,c,h,w] * x2[b,c,h,w+d-80];  B=8 C=128 H=160 W=320 D=81.
//
// Changes vs v1 (510 us / 220 us-dispatch, Occupancy 26%, all pipes idle):
//  - 256-thread blocks (4 waves), w-tile 64, grid 6400: __launch_bounds__(256,6)
//    -> 6 resident blocks/CU (vs 2) = 6 independent barrier domains for TLP.
//  - x1 (A operand) loaded DIRECTLY to registers (each A row is used by exactly
//    one wave -> LDS staging of A was pure overhead). All K=128 preloaded as
//    4x short8 (16 VGPR). Removes lA (23KB LDS) + 40% of stage tiles.
//  - bf16 pack via v_cvt_pk_bf16_f32 (1 inst/pair vs ~12 for manual RNE).
//  - XCD-aware remap: xcd = bid&7 owns batch image b=xcd; the 5 w-tiles of a
//    (b,h) row are adjacent in per-XCD dispatch order -> 80-col x2 halo L2-hits.
//  - Only x2 staged to LDS: 144 rows x ROWP 72 bf16 = 20.7 KB.

#define CB 8
#define CC 128
#define CH 160
#define CW 320
#define CD 81
#define CPAD 80
#define TW 64            // w-tile per block
#define NTHR 256
#define BROWS 144        // TW + 80 halo
#define NTILE 576        // (BROWS/4) * 16 c-quads
#define KC 64
#define ROWP 72          // LDS row stride in bf16 elems (144 B, even bank spread)
#define HW (CH*CW)       // 51200

typedef __attribute__((ext_vector_type(8))) short short8;
typedef __attribute__((ext_vector_type(4))) float f32x4;

__device__ __forceinline__ unsigned cvt_pk(float lo, float hi) {
    // packed fp32->bf16 RNE: D[15:0]=bf16(lo), D[31:16]=bf16(hi)
    unsigned r;
    asm("v_cvt_pk_bf16_f32 %0, %1, %2" : "=v"(r) : "v"(lo), "v"(hi));
    return r;
}

__global__ __launch_bounds__(NTHR, 6) void corr1d_mfma(
    const float* __restrict__ x1,
    const float* __restrict__ x2,
    float* __restrict__ out)
{
    __shared__ __align__(16) unsigned short lB[BROWS * ROWP];  // 20736 B

    const int tid = threadIdx.x;
    const int bid = blockIdx.x;

    // XCD remap: grid 6400 = 8 * 800. xcd = bid&7 gets v in [xcd*800,(xcd+1)*800):
    // g = v/5 = b*160+h (so XCD x owns batch b=x), wt = v%5 innermost -> the
    // 5 w-tiles sharing (b,h) are dispatch-adjacent on one XCD (halo L2 reuse).
    const int v  = (bid & 7) * 800 + (bid >> 3);
    const int g  = v / 5;
    const int wt = v - 5 * g;
    const int b  = g / CH;
    const int h  = g - b * CH;
    const int w0 = wt * TW;

    const int lane = tid & 63;
    const int s    = tid >> 6;   // wave 0..3, owns w-subtile [w0+16s, w0+16s+16)
    const int n    = lane & 15;
    const int q    = lane >> 4;

    const float* x1p = x1 + ((size_t)b * CC * CH + (size_t)h) * CW;
    const float* x2p = x2 + ((size_t)b * CC * CH + (size_t)h) * CW;

    // ---- A preload: all K=128 for this lane's w-row, straight to registers ----
    // A-fragment layout (16x16x32): lane (n,q) holds A[row=n][k=8q+jj].
    short8 aF[4];
    {
        const float* ap = x1p + (size_t)(8 * q) * HW + (w0 + 16 * s + n);
#pragma unroll
        for (int kf = 0; kf < 4; kf++) {
            const float* p = ap + (size_t)(32 * kf) * HW;
            float f0 = p[0];
            float f1 = p[(size_t)1 * HW];
            float f2 = p[(size_t)2 * HW];
            float f3 = p[(size_t)3 * HW];
            float f4 = p[(size_t)4 * HW];
            float f5 = p[(size_t)5 * HW];
            float f6 = p[(size_t)6 * HW];
            float f7 = p[(size_t)7 * HW];
            union { unsigned u[4]; short8 v8; } cv;
            cv.u[0] = cvt_pk(f0, f1);
            cv.u[1] = cvt_pk(f2, f3);
            cv.u[2] = cvt_pk(f4, f5);
            cv.u[3] = cvt_pk(f6, f7);
            aF[kf] = cv.v8;
        }
    }

    f32x4 acc[6];
#pragma unroll
    for (int t = 0; t < 6; t++) acc[t] = (f32x4){0.f, 0.f, 0.f, 0.f};

#pragma unroll
    for (int half = 0; half < 2; half++) {
        const int c0 = half * KC;
        if (half) __syncthreads();  // previous compute done before overwrite

        // ---- stage x2 band: 36 w-row-quads x 16 c-quads = 576 tiles of 4w x 4c ----
#pragma unroll
        for (int j = 0; j < 3; j++) {
            const int i = tid + j * NTHR;
            if (i < NTILE) {
                const int cq = i & 15;
                const int rt = i >> 4;          // 0..35
                const int kl = cq << 2;         // k-local 0..60
                const int gw = w0 - CPAD + (rt << 2);
                float4 v0, v1, v2, v3;
                if (gw >= 0) {
                    const float* p = x2p + (size_t)(c0 + kl) * HW + gw;
                    v0 = *(const float4*)(p);
                    v1 = *(const float4*)(p + (size_t)1 * HW);
                    v2 = *(const float4*)(p + (size_t)2 * HW);
                    v3 = *(const float4*)(p + (size_t)3 * HW);
                } else {
                    v0 = v1 = v2 = v3 = make_float4(0.f, 0.f, 0.f, 0.f);
                }
                // 4x4 transpose + pack, 4 x ds_write_b64
                unsigned short* dst = &lB[(rt << 2) * ROWP + kl];
                *(uint2*)(dst + 0 * ROWP) = make_uint2(cvt_pk(v0.x, v1.x), cvt_pk(v2.x, v3.x));
                *(uint2*)(dst + 1 * ROWP) = make_uint2(cvt_pk(v0.y, v1.y), cvt_pk(v2.y, v3.y));
                *(uint2*)(dst + 2 * ROWP) = make_uint2(cvt_pk(v0.z, v1.z), cvt_pk(v2.z, v3.z));
                *(uint2*)(dst + 3 * ROWP) = make_uint2(cvt_pk(v0.w, v1.w), cvt_pk(v2.w, v3.w));
            }
        }
        __syncthreads();

        // ---- compute: 6 N-tiles x 2 K-steps; A from registers, B from LDS ----
#pragma unroll
        for (int ko = 0; ko < 2; ko++) {
            const short8 av = aF[half * 2 + ko];
            const unsigned short* bb = &lB[(size_t)n * ROWP + ko * 32 + 8 * q];
#pragma unroll
            for (int t = 0; t < 6; t++) {
                short8 bv = *(const short8*)(bb + (size_t)(16 * (s + t)) * ROWP);
                acc[t] = __builtin_amdgcn_mfma_f32_16x16x32_bf16(av, bv, acc[t], 0, 0, 0);
            }
        }
    }

    // ---- epilogue: scatter valid diagonals d = 16t + n - m ----
    float* op = out + ((size_t)b * CD * CH + (size_t)h) * CW + w0 + 16 * s;
#pragma unroll
    for (int t = 0; t < 6; t++) {
#pragma unroll
        for (int r = 0; r < 4; r++) {
            int m = 4 * q + r;
            int d = 16 * t + n - m;
            if (d >= 0 && d <= CPAD)
                op[(size_t)d * HW + m] = acc[t][r];
        }
    }
}

extern "C" void kernel_launch(void* const* d_in, const int* in_sizes, int n_in,
                              void* d_out, int out_size, void* d_ws, size_t ws_size,
                              hipStream_t stream) {
    const float* x1 = (const float*)d_in[0];
    const float* x2 = (const float*)d_in[1];
    float* out = (float*)d_out;
    dim3 grid(CB * CH * 5);   // 6400 = 8 XCD groups x 800
    dim3 block(NTHR);
    corr1d_mfma<<<grid, block, 0, stream>>>(x1, x2, out);
}

// Round 2
// 471.979 us; speedup vs baseline: 1.0822x; 1.0473x over previous
//
#include <hip/hip_runtime.h>

// CorrelationLayer1D via bf16 MFMA band-matmul, v3 (coalesced epilogue).
// out[b,d,h,w] = sum_c x1[b,c,h,w] * x2[b,c,h,w+d-80];  B=8 C=128 H=160 W=320 D=81.
//
// v2 post-mortem: occupancy 26->58% but dur 220->210us. All pipes idle yet 3.4x
// over BW roofline => bottleneck is address-divergence txn cost in the shared
// vector-memory pipe. Dominant term: epilogue scatter (4B/lane at 200KB stride,
// ~54 cache-line txns per store instr, ~26% of runtime).
//
// v3: epilogue transposes acc through LDS (alias of dead lB): eO[81][65] f32.
//  - acc -> eO[d][w_local]: stride-65 rows make the scatter a 4-way bank
//    conflict (cheap); then 81 rows x 64 contiguous floats stored coalesced
//    (4 lines/instr instead of ~54).
//  - everything else unchanged from v2 (A in regs, x2-only staging, XCD remap).

#define CB 8
#define CC 128
#define CH 160
#define CW 320
#define CD 81
#define CPAD 80
#define TW 64            // w-tile per block
#define NTHR 256
#define BROWS 144        // TW + 80 halo
#define NTILE 576        // (BROWS/4) * 16 c-quads
#define KC 64
#define ROWP 72          // LDS row stride in bf16 elems (144 B, even bank spread)
#define EP 65            // epilogue f32 row stride (64 + 1 pad)
#define HW (CH*CW)       // 51200

typedef __attribute__((ext_vector_type(8))) short short8;
typedef __attribute__((ext_vector_type(4))) float f32x4;

__device__ __forceinline__ unsigned cvt_pk(float lo, float hi) {
    // packed fp32->bf16 RNE: D[15:0]=bf16(lo), D[31:16]=bf16(hi)
    unsigned r;
    asm("v_cvt_pk_bf16_f32 %0, %1, %2" : "=v"(r) : "v"(lo), "v"(hi));
    return r;
}

__global__ __launch_bounds__(NTHR, 6) void corr1d_mfma(
    const float* __restrict__ x1,
    const float* __restrict__ x2,
    float* __restrict__ out)
{
    // 21124 B: max(lB 144*72*2 = 20736, eO 81*65*4 = 21060), aliased.
    __shared__ __align__(16) char smem[21072];
    unsigned short* lB = reinterpret_cast<unsigned short*>(smem);
    float* eO = reinterpret_cast<float*>(smem);

    const int tid = threadIdx.x;
    const int bid = blockIdx.x;

    // XCD remap: grid 6400 = 8 * 800. xcd = bid&7 gets v in [xcd*800,(xcd+1)*800):
    // g = v/5 = b*160+h (XCD x owns batch b=x), wt = v%5 innermost -> the
    // 5 w-tiles sharing (b,h) are dispatch-adjacent on one XCD (halo L2 reuse).
    const int v  = (bid & 7) * 800 + (bid >> 3);
    const int g  = v / 5;
    const int wt = v - 5 * g;
    const int b  = g / CH;
    const int h  = g - b * CH;
    const int w0 = wt * TW;

    const int lane = tid & 63;
    const int s    = tid >> 6;   // wave 0..3, owns w-subtile [w0+16s, w0+16s+16)
    const int n    = lane & 15;
    const int q    = lane >> 4;

    const float* x1p = x1 + ((size_t)b * CC * CH + (size_t)h) * CW;
    const float* x2p = x2 + ((size_t)b * CC * CH + (size_t)h) * CW;

    // ---- A preload: all K=128 for this lane's w-row, straight to registers ----
    // A-fragment layout (16x16x32): lane (n,q) holds A[row=n][k=8q+jj].
    short8 aF[4];
    {
        const float* ap = x1p + (size_t)(8 * q) * HW + (w0 + 16 * s + n);
#pragma unroll
        for (int kf = 0; kf < 4; kf++) {
            const float* p = ap + (size_t)(32 * kf) * HW;
            float f0 = p[0];
            float f1 = p[(size_t)1 * HW];
            float f2 = p[(size_t)2 * HW];
            float f3 = p[(size_t)3 * HW];
            float f4 = p[(size_t)4 * HW];
            float f5 = p[(size_t)5 * HW];
            float f6 = p[(size_t)6 * HW];
            float f7 = p[(size_t)7 * HW];
            union { unsigned u[4]; short8 v8; } cv;
            cv.u[0] = cvt_pk(f0, f1);
            cv.u[1] = cvt_pk(f2, f3);
            cv.u[2] = cvt_pk(f4, f5);
            cv.u[3] = cvt_pk(f6, f7);
            aF[kf] = cv.v8;
        }
    }

    f32x4 acc[6];
#pragma unroll
    for (int t = 0; t < 6; t++) acc[t] = (f32x4){0.f, 0.f, 0.f, 0.f};

#pragma unroll
    for (int half = 0; half < 2; half++) {
        const int c0 = half * KC;
        if (half) __syncthreads();  // previous compute done before overwrite

        // ---- stage x2 band: 36 w-row-quads x 16 c-quads = 576 tiles of 4w x 4c ----
#pragma unroll
        for (int j = 0; j < 3; j++) {
            const int i = tid + j * NTHR;
            if (i < NTILE) {
                const int cq = i & 15;
                const int rt = i >> 4;          // 0..35
                const int kl = cq << 2;         // k-local 0..60
                const int gw = w0 - CPAD + (rt << 2);
                float4 v0, v1, v2, v3;
                if (gw >= 0) {
                    const float* p = x2p + (size_t)(c0 + kl) * HW + gw;
                    v0 = *(const float4*)(p);
                    v1 = *(const float4*)(p + (size_t)1 * HW);
                    v2 = *(const float4*)(p + (size_t)2 * HW);
                    v3 = *(const float4*)(p + (size_t)3 * HW);
                } else {
                    v0 = v1 = v2 = v3 = make_float4(0.f, 0.f, 0.f, 0.f);
                }
                // 4x4 transpose + pack, 4 x ds_write_b64
                unsigned short* dst = &lB[(rt << 2) * ROWP + kl];
                *(uint2*)(dst + 0 * ROWP) = make_uint2(cvt_pk(v0.x, v1.x), cvt_pk(v2.x, v3.x));
                *(uint2*)(dst + 1 * ROWP) = make_uint2(cvt_pk(v0.y, v1.y), cvt_pk(v2.y, v3.y));
                *(uint2*)(dst + 2 * ROWP) = make_uint2(cvt_pk(v0.z, v1.z), cvt_pk(v2.z, v3.z));
                *(uint2*)(dst + 3 * ROWP) = make_uint2(cvt_pk(v0.w, v1.w), cvt_pk(v2.w, v3.w));
            }
        }
        __syncthreads();

        // ---- compute: 6 N-tiles x 2 K-steps; A from registers, B from LDS ----
#pragma unroll
        for (int ko = 0; ko < 2; ko++) {
            const short8 av = aF[half * 2 + ko];
            const unsigned short* bb = &lB[(size_t)n * ROWP + ko * 32 + 8 * q];
#pragma unroll
            for (int t = 0; t < 6; t++) {
                short8 bv = *(const short8*)(bb + (size_t)(16 * (s + t)) * ROWP);
                acc[t] = __builtin_amdgcn_mfma_f32_16x16x32_bf16(av, bv, acc[t], 0, 0, 0);
            }
        }
    }

    // ---- epilogue: transpose acc through LDS, then coalesced stores ----
    __syncthreads();   // all ds_reads of lB done before aliasing as eO

#pragma unroll
    for (int t = 0; t < 6; t++) {
#pragma unroll
        for (int r = 0; r < 4; r++) {
            int m = 4 * q + r;
            int d = 16 * t + n - m;
            if (d >= 0 && d <= CPAD)
                eO[d * EP + 16 * s + m] = acc[t][r];
        }
    }
    __syncthreads();

    // 81 rows x 64 contiguous floats; lanes cover w -> 256B coalesced per wave.
    float* op = out + ((size_t)b * CD * CH + (size_t)h) * CW + w0;
#pragma unroll
    for (int j = 0; j < 21; j++) {
        int idx = tid + j * NTHR;     // 0..5375, need < 5184 = 81*64
        if (idx < CD * TW) {
            int d = idx >> 6;
            int w = idx & 63;
            op[(size_t)d * HW + w] = eO[d * EP + w];
        }
    }
}

extern "C" void kernel_launch(void* const* d_in, const int* in_sizes, int n_in,
                              void* d_out, int out_size, void* d_ws, size_t ws_size,
                              hipStream_t stream) {
    const float* x1 = (const float*)d_in[0];
    const float* x2 = (const float*)d_in[1];
    float* out = (float*)d_out;
    dim3 grid(CB * CH * 5);   // 6400 = 8 XCD groups x 800
    dim3 block(NTHR);
    corr1d_mfma<<<grid, block, 0, stream>>>(x1, x2, out);
}

// Round 3
// 469.042 us; speedup vs baseline: 1.0890x; 1.0063x over previous
//
#include <hip/hip_runtime.h>

// CorrelationLayer1D via bf16 MFMA band-matmul, v4 (MLP-oriented rework).
// out[b,d,h,w] = sum_c x1[b,c,h,w] * x2[b,c,h,w+d-80];  B=8 C=128 H=160 W=320 D=81.
//
// v3 post-mortem: dur 210->178us, pipes still idle, VGPR_Count=36 => the
// launch_bounds(256,6) register cap serialized loads into ~10 small
// batch->wait windows per wave. v4 trades occupancy for per-wave MLP:
//  - __launch_bounds__(256,4): VGPR cap 128. A-preload's 32 loads fully in
//    flight; stage tiles batch deeper.
//  - Single K=128 stage phase (lB 144x136 bf16 = 39.2KB): one stage latency
//    window instead of two, barriers 5 -> 3. 4 blocks/CU by LDS.
//  - Epilogue stores as float4 via eO[81][68] (6 store instrs vs 21).
//  - Unchanged: A in regs, x2-only LDS staging, cvt_pk packing, XCD remap.

#define CB 8
#define CC 128
#define CH 160
#define CW 320
#define CD 81
#define CPAD 80
#define TW 64            // w-tile per block
#define NTHR 256
#define BROWS 144        // TW + 80 halo
#define ROWP 136         // LDS B row stride in bf16 elems (K=128 + 8 pad)
#define EP 68            // epilogue f32 row stride (64 + 4, float4-aligned)
#define HW (CH*CW)       // 51200

typedef __attribute__((ext_vector_type(8))) short short8;
typedef __attribute__((ext_vector_type(4))) float f32x4;

__device__ __forceinline__ unsigned cvt_pk(float lo, float hi) {
    // packed fp32->bf16 RNE: D[15:0]=bf16(lo), D[31:16]=bf16(hi)
    unsigned r;
    asm("v_cvt_pk_bf16_f32 %0, %1, %2" : "=v"(r) : "v"(lo), "v"(hi));
    return r;
}

__global__ __launch_bounds__(NTHR, 4) void corr1d_mfma(
    const float* __restrict__ x1,
    const float* __restrict__ x2,
    float* __restrict__ out)
{
    // 39168 B: max(lB 144*136*2 = 39168, eO 81*68*4 = 22032), aliased.
    __shared__ __align__(16) char smem[39168];
    unsigned short* lB = reinterpret_cast<unsigned short*>(smem);
    float* eO = reinterpret_cast<float*>(smem);

    const int tid = threadIdx.x;
    const int bid = blockIdx.x;

    // XCD remap: grid 6400 = 8 * 800. xcd = bid&7 gets v in [xcd*800,(xcd+1)*800):
    // g = v/5 = b*160+h (XCD x owns batch b=x), wt = v%5 innermost -> the
    // 5 w-tiles sharing (b,h) are dispatch-adjacent on one XCD (halo L2 reuse).
    const int v  = (bid & 7) * 800 + (bid >> 3);
    const int g  = v / 5;
    const int wt = v - 5 * g;
    const int b  = g / CH;
    const int h  = g - b * CH;
    const int w0 = wt * TW;

    const int lane = tid & 63;
    const int s    = tid >> 6;   // wave 0..3, owns w-subtile [w0+16s, w0+16s+16)
    const int n    = lane & 15;
    const int q    = lane >> 4;

    const float* x1p = x1 + ((size_t)b * CC * CH + (size_t)h) * CW;
    const float* x2p = x2 + ((size_t)b * CC * CH + (size_t)h) * CW;

    // ---- A preload: all K=128 for this lane's w-row, 32 independent loads ----
    // A-fragment layout (16x16x32): lane (n,q) holds A[row=n][k=8q+jj].
    float araw[32];
    {
        const float* ap = x1p + (size_t)(8 * q) * HW + (w0 + 16 * s + n);
#pragma unroll
        for (int kf = 0; kf < 4; kf++)
#pragma unroll
            for (int j = 0; j < 8; j++)
                araw[kf * 8 + j] = ap[(size_t)(32 * kf + j) * HW];
    }
    short8 aF[4];
#pragma unroll
    for (int kf = 0; kf < 4; kf++) {
        union { unsigned u[4]; short8 v8; } cv;
#pragma unroll
        for (int p = 0; p < 4; p++)
            cv.u[p] = cvt_pk(araw[kf * 8 + 2 * p], araw[kf * 8 + 2 * p + 1]);
        aF[kf] = cv.v8;
    }

    f32x4 acc[6];
#pragma unroll
    for (int t = 0; t < 6; t++) acc[t] = (f32x4){0.f, 0.f, 0.f, 0.f};

    // ---- stage x2 band, full K=128 in ONE phase ----
    // 2 k-halves x (36 w-row-quads x 16 c-quads) = 2 x 576 tiles of 4w x 4c,
    // all loads independent -> one latency window.
#pragma unroll
    for (int khalf = 0; khalf < 2; khalf++) {
        const int c0 = khalf * 64;
#pragma unroll
        for (int j = 0; j < 3; j++) {
            const int i = tid + j * NTHR;
            if (i < 576) {
                const int cq = i & 15;
                const int rt = i >> 4;          // 0..35
                const int kl = cq << 2;         // k-local 0..60
                const int gw = w0 - CPAD + (rt << 2);
                float4 v0, v1, v2, v3;
                if (gw >= 0) {
                    const float* p = x2p + (size_t)(c0 + kl) * HW + gw;
                    v0 = *(const float4*)(p);
                    v1 = *(const float4*)(p + (size_t)1 * HW);
                    v2 = *(const float4*)(p + (size_t)2 * HW);
                    v3 = *(const float4*)(p + (size_t)3 * HW);
                } else {
                    v0 = v1 = v2 = v3 = make_float4(0.f, 0.f, 0.f, 0.f);
                }
                // 4x4 transpose + pack, 4 x ds_write_b64
                unsigned short* dst = &lB[(rt << 2) * ROWP + c0 + kl];
                *(uint2*)(dst + 0 * ROWP) = make_uint2(cvt_pk(v0.x, v1.x), cvt_pk(v2.x, v3.x));
                *(uint2*)(dst + 1 * ROWP) = make_uint2(cvt_pk(v0.y, v1.y), cvt_pk(v2.y, v3.y));
                *(uint2*)(dst + 2 * ROWP) = make_uint2(cvt_pk(v0.z, v1.z), cvt_pk(v2.z, v3.z));
                *(uint2*)(dst + 3 * ROWP) = make_uint2(cvt_pk(v0.w, v1.w), cvt_pk(v2.w, v3.w));
            }
        }
    }
    __syncthreads();

    // ---- compute: 6 N-tiles x 4 K-steps; A from registers, B from LDS ----
#pragma unroll
    for (int ko = 0; ko < 4; ko++) {
        const short8 av = aF[ko];
        const unsigned short* bb = &lB[(size_t)n * ROWP + ko * 32 + 8 * q];
#pragma unroll
        for (int t = 0; t < 6; t++) {
            short8 bv = *(const short8*)(bb + (size_t)(16 * (s + t)) * ROWP);
            acc[t] = __builtin_amdgcn_mfma_f32_16x16x32_bf16(av, bv, acc[t], 0, 0, 0);
        }
    }

    // ---- epilogue: transpose acc through LDS, then float4 coalesced stores ----
    __syncthreads();   // all ds_reads of lB done before aliasing as eO

#pragma unroll
    for (int t = 0; t < 6; t++) {
#pragma unroll
        for (int r = 0; r < 4; r++) {
            int m = 4 * q + r;
            int d = 16 * t + n - m;
            if (d >= 0 && d <= CPAD)
                eO[d * EP + 16 * s + m] = acc[t][r];
        }
    }
    __syncthreads();

    // 81 rows x 16 float4 = 1296 slots; each wave covers 4 rows of 256B.
    float* op = out + ((size_t)b * CD * CH + (size_t)h) * CW + w0;
#pragma unroll
    for (int j = 0; j < 6; j++) {
        int idx = tid + j * NTHR;     // need < 1296 = 81*16
        if (idx < CD * 16) {
            int d  = idx >> 4;
            int wq = idx & 15;
            *(float4*)(op + (size_t)d * HW + 4 * wq) =
                *(const float4*)(&eO[d * EP + 4 * wq]);
        }
    }
}

extern "C" void kernel_launch(void* const* d_in, const int* in_sizes, int n_in,
                              void* d_out, int out_size, void* d_ws, size_t ws_size,
                              hipStream_t stream) {
    const float* x1 = (const float*)d_in[0];
    const float* x2 = (const float*)d_in[1];
    float* out = (float*)d_out;
    dim3 grid(CB * CH * 5);   // 6400 = 8 XCD groups x 800
    dim3 block(NTHR);
    corr1d_mfma<<<grid, block, 0, stream>>>(x1, x2, out);
}